// Round 1
// baseline (3375.798 us; speedup 1.0000x reference)
//
#include <hip/hip_runtime.h>

// MultiheadDiffAttn on MI355X — round 0: correctness-first.
// Pipeline: cast->bf16, 3 MFMA GEMM projections, fp32-VALU flash attention per
// half-head, differential combine + RMSNorm, final MFMA GEMM -> f32 out.

#define B_SZ   2
#define T_LEN  2048
#define E_DIM  2048
#define M_ROWS 4096       // B*T
#define NH     16
#define HH     32         // 2*NH half-heads
#define HD     64         // qk head dim
#define VD     128        // v head dim

#define LAMBDA_INIT_F 0.7836057665316239f
#define ONE_MINUS_LI  0.2163942334683761f

typedef __attribute__((ext_vector_type(4))) float          f32x4;
typedef __attribute__((ext_vector_type(8))) short          s16x8;
typedef __attribute__((ext_vector_type(4))) unsigned short u16x4;
typedef __attribute__((ext_vector_type(8))) __bf16         bf16x8;

__device__ __forceinline__ float bf2f(unsigned short h) {
  union { unsigned u; float f; } v; v.u = ((unsigned)h) << 16; return v.f;
}
__device__ __forceinline__ unsigned short f2bf(float f) {
  union { float f; unsigned u; } v; v.f = f;
  return (unsigned short)((v.u + 0x7fffu + ((v.u >> 16) & 1u)) >> 16);  // RNE
}

// ---------------- cast f32 -> bf16, float4-vectorized ----------------
__global__ __launch_bounds__(256) void cast_bf16(const float* __restrict__ in,
                                                 unsigned short* __restrict__ out,
                                                 int n4) {
  int i = blockIdx.x * 256 + threadIdx.x;
  const int stride = gridDim.x * 256;
  for (; i < n4; i += stride) {
    f32x4 v = ((const f32x4*)in)[i];
    u16x4 o;
    o[0] = f2bf(v[0]); o[1] = f2bf(v[1]); o[2] = f2bf(v[2]); o[3] = f2bf(v[3]);
    ((u16x4*)out)[i] = o;
  }
}

// ---------------- GEMM: C[M,N] = alpha * A(bf16 [M,K]) * B(bf16 [N,K])^T ------
// 128x128 tile, BK=32, 4 waves (2x2), each wave 64x64 via 4x4 mfma_16x16x32.
// LDS XOR-swizzled (kb ^= row&3) to spread the 64B-row-stride fragment reads.
template <int OUT_F32>
__global__ __launch_bounds__(256) void gemm_bt(const unsigned short* __restrict__ A,
                                               const unsigned short* __restrict__ Bm,
                                               void* __restrict__ Cout,
                                               int M, int N, int K, float alpha) {
  __shared__ unsigned short As[128 * 32];
  __shared__ unsigned short Bs[128 * 32];
  const int tid  = threadIdx.x;
  const int lane = tid & 63;
  const int wave = tid >> 6;
  const int wr = wave >> 1, wc = wave & 1;
  const int lrow = lane & 15, lkb = lane >> 4;
  const int m0 = blockIdx.x * 128, n0 = blockIdx.y * 128;

  f32x4 acc[4][4] = {};

  for (int k0 = 0; k0 < K; k0 += 32) {
    // stage: 512 chunks of 16B per matrix; each thread moves 2 of each
#pragma unroll
    for (int cc = 0; cc < 2; ++cc) {
      const int c = tid + cc * 256;
      const int row = c >> 2, kb = c & 3;
      const int kbs = kb ^ (row & 3);
      *(s16x8*)(&As[row * 32 + kbs * 8]) =
          *(const s16x8*)(A + (size_t)(m0 + row) * K + k0 + kb * 8);
      *(s16x8*)(&Bs[row * 32 + kbs * 8]) =
          *(const s16x8*)(Bm + (size_t)(n0 + row) * K + k0 + kb * 8);
    }
    __syncthreads();
    bf16x8 af[4], bfr[4];
#pragma unroll
    for (int mi = 0; mi < 4; ++mi) {
      const int r = wr * 64 + mi * 16 + lrow;
      af[mi] = *(const bf16x8*)(&As[r * 32 + ((lkb ^ (r & 3)) * 8)]);
    }
#pragma unroll
    for (int ni = 0; ni < 4; ++ni) {
      const int r = wc * 64 + ni * 16 + lrow;
      bfr[ni] = *(const bf16x8*)(&Bs[r * 32 + ((lkb ^ (r & 3)) * 8)]);
    }
#pragma unroll
    for (int mi = 0; mi < 4; ++mi)
#pragma unroll
      for (int ni = 0; ni < 4; ++ni)
        acc[mi][ni] = __builtin_amdgcn_mfma_f32_16x16x32_bf16(af[mi], bfr[ni],
                                                              acc[mi][ni], 0, 0, 0);
    __syncthreads();
  }
  // epilogue: D row = (lane>>4)*4 + reg, col = lane&15  (HW-verified mapping)
#pragma unroll
  for (int mi = 0; mi < 4; ++mi) {
#pragma unroll
    for (int ni = 0; ni < 4; ++ni) {
      const int mb = m0 + wr * 64 + mi * 16 + lkb * 4;
      const int nn = n0 + wc * 64 + ni * 16 + lrow;
#pragma unroll
      for (int r = 0; r < 4; ++r) {
        const float v = acc[mi][ni][r] * alpha;
        const size_t idx = (size_t)(mb + r) * N + nn;
        if (OUT_F32) ((float*)Cout)[idx] = v;
        else         ((unsigned short*)Cout)[idx] = f2bf(v);
      }
    }
  }
}

// ---------------- flash attention (fp32 VALU), per (b, half-head, 64-row qtile)
// thread (i = tid>>2, part = tid&3): row i, owns O dims [part*32, part*32+32)
// and computes scores for j = part*8..part*8+7 of each 32-wide K tile.
__global__ __launch_bounds__(256) void flash_attn_valu(
    const unsigned short* __restrict__ Q,   // [B*T, E] bf16 (pre-scaled by D^-0.5)
    const unsigned short* __restrict__ Km,  // [B*T, E] bf16
    const unsigned short* __restrict__ V,   // [B*T, E] bf16
    float* __restrict__ Ohalf) {            // [B, HH, T, VD] f32
  const int qt = blockIdx.x;
  const int hh = blockIdx.y;
  const int b  = blockIdx.z;
  const int tid = threadIdx.x;
  const int i = tid >> 2;
  const int part = tid & 3;
  const int qbase = qt * 64;
  const int h = hh >> 1;

  __shared__ float Ks[32][68];    // padded: 16B-aligned rows, conflict-light
  __shared__ float Vs[32][132];
  __shared__ float Ps[64][36];

  f32x4 q4[16];
  {
    const unsigned short* qrow = Q + ((size_t)(b * T_LEN + qbase + i) * E_DIM + hh * HD);
#pragma unroll
    for (int d8 = 0; d8 < 8; ++d8) {
      s16x8 v = *(const s16x8*)(qrow + d8 * 8);
      f32x4 a, c;
      a[0] = bf2f((unsigned short)v[0]); a[1] = bf2f((unsigned short)v[1]);
      a[2] = bf2f((unsigned short)v[2]); a[3] = bf2f((unsigned short)v[3]);
      c[0] = bf2f((unsigned short)v[4]); c[1] = bf2f((unsigned short)v[5]);
      c[2] = bf2f((unsigned short)v[6]); c[3] = bf2f((unsigned short)v[7]);
      q4[d8 * 2] = a; q4[d8 * 2 + 1] = c;
    }
  }
  f32x4 Ov[8];
#pragma unroll
  for (int d = 0; d < 8; ++d) Ov[d] = (f32x4){0.f, 0.f, 0.f, 0.f};
  float m_run = -1e30f, l_run = 0.f;

  const int ntiles = 2 * qt + 2;  // covers s <= qbase+63
  for (int ti = 0; ti < ntiles; ++ti) {
    const int s0 = ti * 32;
    {   // stage K[32][64], V[32][128] as f32; thread: row tid>>3, chunk tid&7
      const int r = tid >> 3, cb = tid & 7;
      const unsigned short* krow = Km + ((size_t)(b * T_LEN + s0 + r) * E_DIM + hh * HD + cb * 8);
      s16x8 kv = *(const s16x8*)krow;
#pragma unroll
      for (int j = 0; j < 8; ++j) Ks[r][cb * 8 + j] = bf2f((unsigned short)kv[j]);
      const unsigned short* vrow = V + ((size_t)(b * T_LEN + s0 + r) * E_DIM + h * VD + cb * 16);
      s16x8 v0 = *(const s16x8*)vrow;
      s16x8 v1 = *(const s16x8*)(vrow + 8);
#pragma unroll
      for (int j = 0; j < 8; ++j) {
        Vs[r][cb * 16 + j]     = bf2f((unsigned short)v0[j]);
        Vs[r][cb * 16 + 8 + j] = bf2f((unsigned short)v1[j]);
      }
    }
    __syncthreads();
    // scores
    float sc[8];
#pragma unroll
    for (int jj = 0; jj < 8; ++jj) {
      const int j = part * 8 + jj;
      const f32x4* k4 = (const f32x4*)(&Ks[j][0]);
      float a = 0.f;
#pragma unroll
      for (int d4 = 0; d4 < 16; ++d4) {
        f32x4 kv = k4[d4];
        a += q4[d4][0] * kv[0] + q4[d4][1] * kv[1] + q4[d4][2] * kv[2] + q4[d4][3] * kv[3];
      }
      sc[jj] = (s0 + j <= qbase + i) ? a : -1e30f;  // causal mask
    }
    // online softmax (row = 4 consecutive lanes)
    float mloc = sc[0];
#pragma unroll
    for (int jj = 1; jj < 8; ++jj) mloc = fmaxf(mloc, sc[jj]);
    mloc = fmaxf(mloc, __shfl_xor(mloc, 1));
    mloc = fmaxf(mloc, __shfl_xor(mloc, 2));
    const float m_new = fmaxf(m_run, mloc);
    const float resc = __expf(m_run - m_new);
    float ps = 0.f;
#pragma unroll
    for (int jj = 0; jj < 8; ++jj) {
      const float pv = __expf(sc[jj] - m_new);
      ps += pv;
      Ps[i][part * 8 + jj] = pv;
    }
    ps += __shfl_xor(ps, 1);
    ps += __shfl_xor(ps, 2);
    l_run = l_run * resc + ps;
    m_run = m_new;
#pragma unroll
    for (int d = 0; d < 8; ++d) {
      Ov[d][0] *= resc; Ov[d][1] *= resc; Ov[d][2] *= resc; Ov[d][3] *= resc;
    }
    __syncthreads();   // Ps visible
    // PV
#pragma unroll 4
    for (int j = 0; j < 32; ++j) {
      const float pj = Ps[i][j];
      const f32x4* v4 = (const f32x4*)(&Vs[j][part * 32]);
#pragma unroll
      for (int dd = 0; dd < 8; ++dd) {
        f32x4 vv = v4[dd];
        Ov[dd][0] += pj * vv[0]; Ov[dd][1] += pj * vv[1];
        Ov[dd][2] += pj * vv[2]; Ov[dd][3] += pj * vv[3];
      }
    }
    __syncthreads();   // before next stage overwrites Ks/Vs
  }
  const float rn = 1.f / l_run;
  float* orow = Ohalf + (((size_t)(b * HH + hh) * T_LEN + qbase + i) * VD + part * 32);
#pragma unroll
  for (int dd = 0; dd < 8; ++dd) {
    f32x4 o;
    o[0] = Ov[dd][0] * rn; o[1] = Ov[dd][1] * rn;
    o[2] = Ov[dd][2] * rn; o[3] = Ov[dd][3] * rn;
    ((f32x4*)orow)[dd] = o;
  }
}

// ---------------- differential combine + RMSNorm -> act bf16 [B*T, E] --------
__global__ __launch_bounds__(64) void combine_norm(
    const float* __restrict__ Oh,
    const float* __restrict__ lq1, const float* __restrict__ lk1,
    const float* __restrict__ lq2, const float* __restrict__ lk2,
    const float* __restrict__ g,
    unsigned short* __restrict__ Act) {
  const int lane = threadIdx.x;
  const int r = blockIdx.x;          // (b*T + t)*NH + h
  const int hd = r & 15;
  const int t = (r >> 4) & 2047;
  const int b = r >> 15;
  float p1 = lq1[lane] * lk1[lane];
  float p2 = lq2[lane] * lk2[lane];
#pragma unroll
  for (int o = 1; o < 64; o <<= 1) { p1 += __shfl_xor(p1, o); p2 += __shfl_xor(p2, o); }
  const float lam = __expf(p1) - __expf(p2) + LAMBDA_INIT_F;
  const float* o0 = Oh + ((size_t)(b * HH + 2 * hd) * T_LEN + t) * VD;
  const float* o1 = o0 + (size_t)T_LEN * VD;
  const float x0 = o0[lane]      - lam * o1[lane];
  const float x1 = o0[lane + 64] - lam * o1[lane + 64];
  float ss = x0 * x0 + x1 * x1;
#pragma unroll
  for (int o = 1; o < 64; o <<= 1) ss += __shfl_xor(ss, o);
  const float s = rsqrtf(ss * (1.f / 128.f) + 1e-5f) * ONE_MINUS_LI;
  unsigned short* arow = Act + ((size_t)(b * T_LEN + t) * E_DIM + hd * VD);
  arow[lane]      = f2bf(x0 * s * g[lane]);
  arow[lane + 64] = f2bf(x1 * s * g[lane + 64]);
}

extern "C" void kernel_launch(void* const* d_in, const int* in_sizes, int n_in,
                              void* d_out, int out_size, void* d_ws, size_t ws_size,
                              hipStream_t stream) {
  (void)in_sizes; (void)n_in; (void)out_size; (void)ws_size;
  const float* x   = (const float*)d_in[0];
  const float* Wq  = (const float*)d_in[1];
  const float* Wk  = (const float*)d_in[2];
  const float* Wv  = (const float*)d_in[3];
  const float* Wo  = (const float*)d_in[4];
  const float* lq1 = (const float*)d_in[5];
  const float* lk1 = (const float*)d_in[6];
  const float* lq2 = (const float*)d_in[7];
  const float* lk2 = (const float*)d_in[8];
  const float* g   = (const float*)d_in[9];

  // workspace layout (184.6 MB total)
  char* p = (char*)d_ws;
  unsigned short* XBF = (unsigned short*)p; p += (size_t)M_ROWS * E_DIM * 2;
  unsigned short* WQB = (unsigned short*)p; p += (size_t)E_DIM * E_DIM * 2;
  unsigned short* WKB = (unsigned short*)p; p += (size_t)E_DIM * E_DIM * 2;
  unsigned short* WVB = (unsigned short*)p; p += (size_t)E_DIM * E_DIM * 2;
  unsigned short* WOB = (unsigned short*)p; p += (size_t)E_DIM * E_DIM * 2;
  unsigned short* QB  = (unsigned short*)p; p += (size_t)M_ROWS * E_DIM * 2;
  unsigned short* KB  = (unsigned short*)p; p += (size_t)M_ROWS * E_DIM * 2;
  unsigned short* VB  = (unsigned short*)p; p += (size_t)M_ROWS * E_DIM * 2;
  float*          OH  = (float*)p;          p += (size_t)B_SZ * HH * T_LEN * VD * 4;
  unsigned short* ACT = (unsigned short*)p; p += (size_t)M_ROWS * E_DIM * 2;

  cast_bf16<<<2048, 256, 0, stream>>>(x,  XBF, M_ROWS * E_DIM / 4);
  cast_bf16<<<1024, 256, 0, stream>>>(Wq, WQB, E_DIM * E_DIM / 4);
  cast_bf16<<<1024, 256, 0, stream>>>(Wk, WKB, E_DIM * E_DIM / 4);
  cast_bf16<<<1024, 256, 0, stream>>>(Wv, WVB, E_DIM * E_DIM / 4);
  cast_bf16<<<1024, 256, 0, stream>>>(Wo, WOB, E_DIM * E_DIM / 4);

  dim3 gg(M_ROWS / 128, E_DIM / 128);
  gemm_bt<0><<<gg, 256, 0, stream>>>(XBF, WQB, QB, M_ROWS, E_DIM, E_DIM, 0.125f); // q * D^-0.5
  gemm_bt<0><<<gg, 256, 0, stream>>>(XBF, WKB, KB, M_ROWS, E_DIM, E_DIM, 1.0f);
  gemm_bt<0><<<gg, 256, 0, stream>>>(XBF, WVB, VB, M_ROWS, E_DIM, E_DIM, 1.0f);

  flash_attn_valu<<<dim3(T_LEN / 64, HH, B_SZ), 256, 0, stream>>>(QB, KB, VB, OH);

  combine_norm<<<B_SZ * T_LEN * NH, 64, 0, stream>>>(OH, lq1, lk1, lq2, lk2, g, ACT);

  gemm_bt<1><<<gg, 256, 0, stream>>>(ACT, WOB, d_out, M_ROWS, E_DIM, E_DIM, 1.0f);
}

// Round 2
// 983.999 us; speedup vs baseline: 3.4307x; 3.4307x over previous
//
#include <hip/hip_runtime.h>

// MultiheadDiffAttn on MI355X — round 2: MFMA flash attention.
// Pipeline: cast->bf16, 3 MFMA GEMM projections, MFMA flash attention per
// half-head, differential combine + RMSNorm, final MFMA GEMM -> f32 out.

#define B_SZ   2
#define T_LEN  2048
#define E_DIM  2048
#define M_ROWS 4096       // B*T
#define NH     16
#define HH     32         // 2*NH half-heads
#define HD     64         // qk head dim
#define VD     128        // v head dim

#define LAMBDA_INIT_F 0.7836057665316239f
#define ONE_MINUS_LI  0.2163942334683761f

typedef __attribute__((ext_vector_type(4))) float          f32x4;
typedef __attribute__((ext_vector_type(8))) short          s16x8;
typedef __attribute__((ext_vector_type(4))) unsigned short u16x4;
typedef __attribute__((ext_vector_type(8))) __bf16         bf16x8;

__device__ __forceinline__ float bf2f(unsigned short h) {
  union { unsigned u; float f; } v; v.u = ((unsigned)h) << 16; return v.f;
}
__device__ __forceinline__ unsigned short f2bf(float f) {
  union { float f; unsigned u; } v; v.f = f;
  return (unsigned short)((v.u + 0x7fffu + ((v.u >> 16) & 1u)) >> 16);  // RNE
}

// ---------------- cast f32 -> bf16, float4-vectorized ----------------
__global__ __launch_bounds__(256) void cast_bf16(const float* __restrict__ in,
                                                 unsigned short* __restrict__ out,
                                                 int n4) {
  int i = blockIdx.x * 256 + threadIdx.x;
  const int stride = gridDim.x * 256;
  for (; i < n4; i += stride) {
    f32x4 v = ((const f32x4*)in)[i];
    u16x4 o;
    o[0] = f2bf(v[0]); o[1] = f2bf(v[1]); o[2] = f2bf(v[2]); o[3] = f2bf(v[3]);
    ((u16x4*)out)[i] = o;
  }
}

// ---------------- GEMM: C[M,N] = alpha * A(bf16 [M,K]) * B(bf16 [N,K])^T ------
template <int OUT_F32>
__global__ __launch_bounds__(256) void gemm_bt(const unsigned short* __restrict__ A,
                                               const unsigned short* __restrict__ Bm,
                                               void* __restrict__ Cout,
                                               int M, int N, int K, float alpha) {
  __shared__ unsigned short As[128 * 32];
  __shared__ unsigned short Bs[128 * 32];
  const int tid  = threadIdx.x;
  const int lane = tid & 63;
  const int wave = tid >> 6;
  const int wr = wave >> 1, wc = wave & 1;
  const int lrow = lane & 15, lkb = lane >> 4;
  const int m0 = blockIdx.x * 128, n0 = blockIdx.y * 128;

  f32x4 acc[4][4] = {};

  for (int k0 = 0; k0 < K; k0 += 32) {
#pragma unroll
    for (int cc = 0; cc < 2; ++cc) {
      const int c = tid + cc * 256;
      const int row = c >> 2, kb = c & 3;
      const int kbs = kb ^ (row & 3);
      *(s16x8*)(&As[row * 32 + kbs * 8]) =
          *(const s16x8*)(A + (size_t)(m0 + row) * K + k0 + kb * 8);
      *(s16x8*)(&Bs[row * 32 + kbs * 8]) =
          *(const s16x8*)(Bm + (size_t)(n0 + row) * K + k0 + kb * 8);
    }
    __syncthreads();
    bf16x8 af[4], bfr[4];
#pragma unroll
    for (int mi = 0; mi < 4; ++mi) {
      const int r = wr * 64 + mi * 16 + lrow;
      af[mi] = *(const bf16x8*)(&As[r * 32 + ((lkb ^ (r & 3)) * 8)]);
    }
#pragma unroll
    for (int ni = 0; ni < 4; ++ni) {
      const int r = wc * 64 + ni * 16 + lrow;
      bfr[ni] = *(const bf16x8*)(&Bs[r * 32 + ((lkb ^ (r & 3)) * 8)]);
    }
#pragma unroll
    for (int mi = 0; mi < 4; ++mi)
#pragma unroll
      for (int ni = 0; ni < 4; ++ni)
        acc[mi][ni] = __builtin_amdgcn_mfma_f32_16x16x32_bf16(af[mi], bfr[ni],
                                                              acc[mi][ni], 0, 0, 0);
    __syncthreads();
  }
#pragma unroll
  for (int mi = 0; mi < 4; ++mi) {
#pragma unroll
    for (int ni = 0; ni < 4; ++ni) {
      const int mb = m0 + wr * 64 + mi * 16 + lkb * 4;
      const int nn = n0 + wc * 64 + ni * 16 + lrow;
#pragma unroll
      for (int r = 0; r < 4; ++r) {
        const float v = acc[mi][ni][r] * alpha;
        const size_t idx = (size_t)(mb + r) * N + nn;
        if (OUT_F32) ((float*)Cout)[idx] = v;
        else         ((unsigned short*)Cout)[idx] = f2bf(v);
      }
    }
  }
}

// ---------------- MFMA flash attention ----------------
// Block = 4 waves, per (b, half-head, 128-row Q tile). Wave w owns rows
// qbase + w*32 .. +31 (2 x 16-row mfma tiles). KV step = 64.
// LDS: Ks[64][64] bf16 row-major XOR-swizzled; Vt[128][64] transposed
// XOR-swizzled; Pl[128][64] wave-private P tiles, XOR-swizzled.
// All swizzles: 16B chunk index ^= (row & 7).
__global__ __launch_bounds__(256, 3) void flash_attn_mfma(
    const unsigned short* __restrict__ Q,   // [B*T, E] bf16 (pre-scaled by D^-0.5)
    const unsigned short* __restrict__ Km,  // [B*T, E] bf16
    const unsigned short* __restrict__ V,   // [B*T, E] bf16
    float* __restrict__ Ohalf) {            // [B, HH, T, VD] f32
  const int qt = blockIdx.x;
  const int hh = blockIdx.y;
  const int b  = blockIdx.z;
  const int tid  = threadIdx.x;
  const int lane = tid & 63;
  const int wave = tid >> 6;
  const int g  = lane >> 4;      // 16-lane group 0..3
  const int lr = lane & 15;
  const int qbase = qt * 128;
  const int h = hh >> 1;
  const size_t bT = (size_t)b * T_LEN;

  __shared__ unsigned short Ks[64 * 64];
  __shared__ unsigned short Vt[128 * 64];
  __shared__ unsigned short Pl[128 * 64];

  // Q fragments (held in registers for the whole block)
  bf16x8 qf[2][2];
#pragma unroll
  for (int mi = 0; mi < 2; ++mi)
#pragma unroll
    for (int kc = 0; kc < 2; ++kc) {
      const int row = qbase + wave * 32 + mi * 16 + lr;
      qf[mi][kc] = *(const bf16x8*)(Q + (bT + row) * E_DIM + hh * HD + kc * 32 + g * 8);
    }

  f32x4 Oa[2][8];
#pragma unroll
  for (int mi = 0; mi < 2; ++mi)
#pragma unroll
    for (int dv = 0; dv < 8; ++dv) Oa[mi][dv] = (f32x4){0.f, 0.f, 0.f, 0.f};
  float m_run[2][4], l_run[2][4];
#pragma unroll
  for (int mi = 0; mi < 2; ++mi)
#pragma unroll
    for (int r = 0; r < 4; ++r) { m_run[mi][r] = -1e30f; l_run[mi][r] = 0.f; }

  const int nsteps = 2 * qt + 2;
  for (int ti = 0; ti < nsteps; ++ti) {
    const int s0 = ti * 64;
    __syncthreads();     // previous step's K/V reads complete
    {   // stage K[64][64]: thread -> (srow = tid>>3 (+32), chunk c = tid&7)
      const int c = tid & 7;
#pragma unroll
      for (int j = 0; j < 2; ++j) {
        const int s = (tid >> 3) + j * 32;
        s16x8 kv = *(const s16x8*)(Km + (bT + s0 + s) * E_DIM + hh * HD + c * 8);
        *(s16x8*)(&Ks[s * 64 + ((c ^ (s & 7)) * 8)]) = kv;
      }
      // stage Vt (transposed): thread -> (s = tid&63, d-block = tid>>6)
      const int s = tid & 63;
#pragma unroll
      for (int cc = 0; cc < 4; ++cc) {
        const int d0 = ((tid >> 6) + cc * 4) * 8;
        s16x8 vv = *(const s16x8*)(V + (bT + s0 + s) * E_DIM + h * VD + d0);
#pragma unroll
        for (int u = 0; u < 8; ++u) {
          const int d = d0 + u;
          Vt[d * 64 + (((s >> 3) ^ (d & 7)) * 8) + (s & 7)] = (unsigned short)vv[u];
        }
      }
    }
    __syncthreads();     // staging visible

    // ---- QK^T ----
    bf16x8 kb[4][2];
#pragma unroll
    for (int nj = 0; nj < 4; ++nj)
#pragma unroll
      for (int kc = 0; kc < 2; ++kc) {
        const int srow = nj * 16 + lr;
        kb[nj][kc] = *(const bf16x8*)(&Ks[srow * 64 + (((kc * 4 + g) ^ (srow & 7)) * 8)]);
      }
    f32x4 Sa[2][4];
#pragma unroll
    for (int mi = 0; mi < 2; ++mi)
#pragma unroll
      for (int nj = 0; nj < 4; ++nj) {
        f32x4 acc = (f32x4){0.f, 0.f, 0.f, 0.f};
#pragma unroll
        for (int kc = 0; kc < 2; ++kc)
          acc = __builtin_amdgcn_mfma_f32_16x16x32_bf16(qf[mi][kc], kb[nj][kc], acc, 0, 0, 0);
        Sa[mi][nj] = acc;
      }

    // ---- causal mask + online softmax (rows are lane-group-local) ----
#pragma unroll
    for (int mi = 0; mi < 2; ++mi) {
      const int rowb = qbase + wave * 32 + mi * 16 + g * 4;
#pragma unroll
      for (int r = 0; r < 4; ++r) {
        float mx = -1e30f;
#pragma unroll
        for (int nj = 0; nj < 4; ++nj) {
          const int col = s0 + nj * 16 + lr;
          const float v = (col <= rowb + r) ? Sa[mi][nj][r] : -1e30f;
          Sa[mi][nj][r] = v;
          mx = fmaxf(mx, v);
        }
        mx = fmaxf(mx, __shfl_xor(mx, 1));
        mx = fmaxf(mx, __shfl_xor(mx, 2));
        mx = fmaxf(mx, __shfl_xor(mx, 4));
        mx = fmaxf(mx, __shfl_xor(mx, 8));
        const float mn = fmaxf(m_run[mi][r], mx);
        const float rs = __expf(m_run[mi][r] - mn);
        m_run[mi][r] = mn;
        float ps = 0.f;
#pragma unroll
        for (int nj = 0; nj < 4; ++nj) {
          const float p = __expf(Sa[mi][nj][r] - mn);
          Sa[mi][nj][r] = p;
          ps += p;
        }
        ps += __shfl_xor(ps, 1);
        ps += __shfl_xor(ps, 2);
        ps += __shfl_xor(ps, 4);
        ps += __shfl_xor(ps, 8);
        l_run[mi][r] = l_run[mi][r] * rs + ps;
#pragma unroll
        for (int dv = 0; dv < 8; ++dv) Oa[mi][dv][r] *= rs;
      }
      // write P (bf16) into wave-private LDS rows — no barrier needed
#pragma unroll
      for (int nj = 0; nj < 4; ++nj)
#pragma unroll
        for (int r = 0; r < 4; ++r) {
          const int row = wave * 32 + mi * 16 + g * 4 + r;
          const int chunk = (nj * 2 + (lr >> 3)) ^ (row & 7);
          Pl[row * 64 + chunk * 8 + (lr & 7)] = f2bf(Sa[mi][nj][r]);
        }
    }

    // ---- PV ----
    bf16x8 pa[2][2];
#pragma unroll
    for (int mi = 0; mi < 2; ++mi)
#pragma unroll
      for (int kc = 0; kc < 2; ++kc) {
        const int row = wave * 32 + mi * 16 + lr;
        pa[mi][kc] = *(const bf16x8*)(&Pl[row * 64 + (((kc * 4 + g) ^ (row & 7)) * 8)]);
      }
#pragma unroll
    for (int dv = 0; dv < 8; ++dv) {
      bf16x8 vb[2];
#pragma unroll
      for (int kc = 0; kc < 2; ++kc) {
        const int d = dv * 16 + lr;
        vb[kc] = *(const bf16x8*)(&Vt[d * 64 + (((kc * 4 + g) ^ (d & 7)) * 8)]);
      }
#pragma unroll
      for (int mi = 0; mi < 2; ++mi)
#pragma unroll
        for (int kc = 0; kc < 2; ++kc)
          Oa[mi][dv] = __builtin_amdgcn_mfma_f32_16x16x32_bf16(pa[mi][kc], vb[kc],
                                                               Oa[mi][dv], 0, 0, 0);
    }
  }

  // ---- epilogue: normalize and store ----
#pragma unroll
  for (int mi = 0; mi < 2; ++mi) {
    float rn[4];
#pragma unroll
    for (int r = 0; r < 4; ++r) rn[r] = 1.f / l_run[mi][r];
#pragma unroll
    for (int dv = 0; dv < 8; ++dv)
#pragma unroll
      for (int r = 0; r < 4; ++r) {
        const int t = qbase + wave * 32 + mi * 16 + g * 4 + r;
        Ohalf[(((size_t)(b * HH + hh) * T_LEN + t) * VD) + dv * 16 + lr] =
            Oa[mi][dv][r] * rn[r];
      }
  }
}

// ---------------- differential combine + RMSNorm -> act bf16 [B*T, E] --------
__global__ __launch_bounds__(64) void combine_norm(
    const float* __restrict__ Oh,
    const float* __restrict__ lq1, const float* __restrict__ lk1,
    const float* __restrict__ lq2, const float* __restrict__ lk2,
    const float* __restrict__ g,
    unsigned short* __restrict__ Act) {
  const int lane = threadIdx.x;
  const int r = blockIdx.x;          // (b*T + t)*NH + h
  const int hd = r & 15;
  const int t = (r >> 4) & 2047;
  const int b = r >> 15;
  float p1 = lq1[lane] * lk1[lane];
  float p2 = lq2[lane] * lk2[lane];
#pragma unroll
  for (int o = 1; o < 64; o <<= 1) { p1 += __shfl_xor(p1, o); p2 += __shfl_xor(p2, o); }
  const float lam = __expf(p1) - __expf(p2) + LAMBDA_INIT_F;
  const float* o0 = Oh + ((size_t)(b * HH + 2 * hd) * T_LEN + t) * VD;
  const float* o1 = o0 + (size_t)T_LEN * VD;
  const float x0 = o0[lane]      - lam * o1[lane];
  const float x1 = o0[lane + 64] - lam * o1[lane + 64];
  float ss = x0 * x0 + x1 * x1;
#pragma unroll
  for (int o = 1; o < 64; o <<= 1) ss += __shfl_xor(ss, o);
  const float s = rsqrtf(ss * (1.f / 128.f) + 1e-5f) * ONE_MINUS_LI;
  unsigned short* arow = Act + ((size_t)(b * T_LEN + t) * E_DIM + hd * VD);
  arow[lane]      = f2bf(x0 * s * g[lane]);
  arow[lane + 64] = f2bf(x1 * s * g[lane + 64]);
}

extern "C" void kernel_launch(void* const* d_in, const int* in_sizes, int n_in,
                              void* d_out, int out_size, void* d_ws, size_t ws_size,
                              hipStream_t stream) {
  (void)in_sizes; (void)n_in; (void)out_size; (void)ws_size;
  const float* x   = (const float*)d_in[0];
  const float* Wq  = (const float*)d_in[1];
  const float* Wk  = (const float*)d_in[2];
  const float* Wv  = (const float*)d_in[3];
  const float* Wo  = (const float*)d_in[4];
  const float* lq1 = (const float*)d_in[5];
  const float* lk1 = (const float*)d_in[6];
  const float* lq2 = (const float*)d_in[7];
  const float* lk2 = (const float*)d_in[8];
  const float* g   = (const float*)d_in[9];

  char* p = (char*)d_ws;
  unsigned short* XBF = (unsigned short*)p; p += (size_t)M_ROWS * E_DIM * 2;
  unsigned short* WQB = (unsigned short*)p; p += (size_t)E_DIM * E_DIM * 2;
  unsigned short* WKB = (unsigned short*)p; p += (size_t)E_DIM * E_DIM * 2;
  unsigned short* WVB = (unsigned short*)p; p += (size_t)E_DIM * E_DIM * 2;
  unsigned short* WOB = (unsigned short*)p; p += (size_t)E_DIM * E_DIM * 2;
  unsigned short* QB  = (unsigned short*)p; p += (size_t)M_ROWS * E_DIM * 2;
  unsigned short* KB  = (unsigned short*)p; p += (size_t)M_ROWS * E_DIM * 2;
  unsigned short* VB  = (unsigned short*)p; p += (size_t)M_ROWS * E_DIM * 2;
  float*          OH  = (float*)p;          p += (size_t)B_SZ * HH * T_LEN * VD * 4;
  unsigned short* ACT = (unsigned short*)p; p += (size_t)M_ROWS * E_DIM * 2;

  cast_bf16<<<2048, 256, 0, stream>>>(x,  XBF, M_ROWS * E_DIM / 4);
  cast_bf16<<<1024, 256, 0, stream>>>(Wq, WQB, E_DIM * E_DIM / 4);
  cast_bf16<<<1024, 256, 0, stream>>>(Wk, WKB, E_DIM * E_DIM / 4);
  cast_bf16<<<1024, 256, 0, stream>>>(Wv, WVB, E_DIM * E_DIM / 4);
  cast_bf16<<<1024, 256, 0, stream>>>(Wo, WOB, E_DIM * E_DIM / 4);

  dim3 gg(M_ROWS / 128, E_DIM / 128);
  gemm_bt<0><<<gg, 256, 0, stream>>>(XBF, WQB, QB, M_ROWS, E_DIM, E_DIM, 0.125f); // q * D^-0.5
  gemm_bt<0><<<gg, 256, 0, stream>>>(XBF, WKB, KB, M_ROWS, E_DIM, E_DIM, 1.0f);
  gemm_bt<0><<<gg, 256, 0, stream>>>(XBF, WVB, VB, M_ROWS, E_DIM, E_DIM, 1.0f);

  flash_attn_mfma<<<dim3(T_LEN / 128, HH, B_SZ), 256, 0, stream>>>(QB, KB, VB, OH);

  combine_norm<<<B_SZ * T_LEN * NH, 64, 0, stream>>>(OH, lq1, lk1, lq2, lk2, g, ACT);

  gemm_bt<1><<<gg, 256, 0, stream>>>(ACT, WOB, d_out, M_ROWS, E_DIM, E_DIM, 1.0f);
}

// Round 4
// 520.832 us; speedup vs baseline: 6.4816x; 1.8893x over previous
//
#include <hip/hip_runtime.h>

// MultiheadDiffAttn on MI355X — round 3 (resubmit after infra failure):
// balanced paired-tile flash with async dbuf staging (global_load_lds),
// V^T via GEMM operand swap, and global_load_lds staging in the GEMMs.

#define B_SZ   2
#define T_LEN  2048
#define E_DIM  2048
#define M_ROWS 4096       // B*T
#define NH     16
#define HH     32         // 2*NH half-heads
#define HD     64         // qk head dim
#define VD     128        // v head dim
#define NQT    16         // T_LEN/128 q-tiles

#define LAMBDA_INIT_F 0.7836057665316239f
#define ONE_MINUS_LI  0.2163942334683761f

typedef __attribute__((ext_vector_type(4))) float          f32x4;
typedef __attribute__((ext_vector_type(8))) short          s16x8;
typedef __attribute__((ext_vector_type(4))) unsigned short u16x4;
typedef __attribute__((ext_vector_type(8))) __bf16         bf16x8;

typedef const __attribute__((address_space(1))) unsigned int* gas_t;
typedef __attribute__((address_space(3))) unsigned int*       las_t;
// async global->LDS, 16B per lane; LDS dest = wave-uniform base + lane*16.
__device__ __forceinline__ void gl_lds16(const void* g, void* l) {
  __builtin_amdgcn_global_load_lds((gas_t)g, (las_t)l, 16, 0, 0);
}

__device__ __forceinline__ float bf2f(unsigned short h) {
  union { unsigned u; float f; } v; v.u = ((unsigned)h) << 16; return v.f;
}
__device__ __forceinline__ unsigned short f2bf(float f) {
  union { float f; unsigned u; } v; v.f = f;
  return (unsigned short)((v.u + 0x7fffu + ((v.u >> 16) & 1u)) >> 16);  // RNE
}

// ---------------- cast f32 -> bf16, float4-vectorized ----------------
__global__ __launch_bounds__(256) void cast_bf16(const float* __restrict__ in,
                                                 unsigned short* __restrict__ out,
                                                 int n4) {
  int i = blockIdx.x * 256 + threadIdx.x;
  const int stride = gridDim.x * 256;
  for (; i < n4; i += stride) {
    f32x4 v = ((const f32x4*)in)[i];
    u16x4 o;
    o[0] = f2bf(v[0]); o[1] = f2bf(v[1]); o[2] = f2bf(v[2]); o[3] = f2bf(v[3]);
    ((u16x4*)out)[i] = o;
  }
}

// ---------------- GEMM: C[M,N] = alpha * A(bf16 [M,K]) * B(bf16 [N,K])^T ------
// 128x128 tile, BK=32, 4 waves. Staging via global_load_lds (16B), LDS layout
// phys[row][x] = A[row][x ^ (row&3)] (pre-swizzled global source, linear dest).
template <int OUT_F32>
__global__ __launch_bounds__(256) void gemm_bt(const unsigned short* __restrict__ A,
                                               const unsigned short* __restrict__ Bm,
                                               void* __restrict__ Cout,
                                               int M, int N, int K, float alpha) {
  __shared__ unsigned short As[128 * 32];
  __shared__ unsigned short Bs[128 * 32];
  const int tid  = threadIdx.x;
  const int lane = tid & 63;
  const int wave = tid >> 6;
  const int wr = wave >> 1, wc = wave & 1;
  const int lrow = lane & 15, lkb = lane >> 4;
  const int m0 = blockIdx.x * 128, n0 = blockIdx.y * 128;

  f32x4 acc[4][4] = {};

  for (int k0 = 0; k0 < K; k0 += 32) {
#pragma unroll
    for (int cc = 0; cc < 2; ++cc) {
      const int ci  = tid + cc * 256;          // 0..511
      const int row = ci >> 2;
      const int kbs = (ci & 3) ^ (row & 3);    // pre-swizzled source chunk
      const int rb  = (wave * 16 + cc * 64) * 32;  // wave-uniform LDS base (elems)
      gl_lds16(A  + (size_t)(m0 + row) * K + k0 + kbs * 8, &As[rb]);
      gl_lds16(Bm + (size_t)(n0 + row) * K + k0 + kbs * 8, &Bs[rb]);
    }
    __syncthreads();
    bf16x8 af[4], bfr[4];
#pragma unroll
    for (int mi = 0; mi < 4; ++mi) {
      const int r = wr * 64 + mi * 16 + lrow;
      af[mi] = *(const bf16x8*)(&As[r * 32 + ((lkb ^ (r & 3)) * 8)]);
    }
#pragma unroll
    for (int ni = 0; ni < 4; ++ni) {
      const int r = wc * 64 + ni * 16 + lrow;
      bfr[ni] = *(const bf16x8*)(&Bs[r * 32 + ((lkb ^ (r & 3)) * 8)]);
    }
#pragma unroll
    for (int mi = 0; mi < 4; ++mi)
#pragma unroll
      for (int ni = 0; ni < 4; ++ni)
        acc[mi][ni] = __builtin_amdgcn_mfma_f32_16x16x32_bf16(af[mi], bfr[ni],
                                                              acc[mi][ni], 0, 0, 0);
    __syncthreads();
  }
#pragma unroll
  for (int mi = 0; mi < 4; ++mi) {
#pragma unroll
    for (int ni = 0; ni < 4; ++ni) {
      const int mb = m0 + wr * 64 + mi * 16 + lkb * 4;
      const int nn = n0 + wc * 64 + ni * 16 + lrow;
#pragma unroll
      for (int r = 0; r < 4; ++r) {
        const float v = acc[mi][ni][r] * alpha;
        const size_t idx = (size_t)(mb + r) * N + nn;
        if (OUT_F32) ((float*)Cout)[idx] = v;
        else         ((unsigned short*)Cout)[idx] = f2bf(v);
      }
    }
  }
}

// ---------------- MFMA flash attention (paired tiles, async dbuf staging) ----
// Block = 4 waves, handles q-tiles {pr, 15-pr} for one (b, half-head): exactly
// 34 KV-steps per block. K staged [64][64] swizzled; V^T staged [128][64]
// swizzled (input VT is [E][M_ROWS] from the operand-swapped V GEMM).
__device__ __forceinline__ void stage_kv(const unsigned short* __restrict__ Kbase,
                                         const unsigned short* __restrict__ Vbase,
                                         int s0, unsigned short* KsBuf,
                                         unsigned short* VtBuf, int tid, int wave) {
#pragma unroll
  for (int j = 0; j < 2; ++j) {       // K: 64 rows x 64 elems
    const int ci = tid + j * 256;
    const int s = ci >> 3;
    const int cs = (ci & 7) ^ (s & 7);
    gl_lds16(Kbase + (size_t)(s0 + s) * E_DIM + cs * 8, KsBuf + (wave * 64 + j * 256) * 8);
  }
#pragma unroll
  for (int cc = 0; cc < 4; ++cc) {    // V^T: 128 rows x 64 elems
    const int ci = tid + cc * 256;
    const int d = ci >> 3;
    const int cs = (ci & 7) ^ (d & 7);
    gl_lds16(Vbase + (size_t)d * M_ROWS + s0 + cs * 8, VtBuf + (wave * 64 + cc * 256) * 8);
  }
}

__global__ __launch_bounds__(256, 2) void flash_attn_mfma(
    const unsigned short* __restrict__ Q,   // [B*T, E] bf16 (pre-scaled by D^-0.5)
    const unsigned short* __restrict__ Km,  // [B*T, E] bf16
    const unsigned short* __restrict__ VT,  // [E, B*T] bf16 (V transposed)
    float* __restrict__ Ohalf) {            // [B, HH, T, VD] f32
  const int pr = blockIdx.x;                // pair 0..7
  const int hh = blockIdx.y;
  const int b  = blockIdx.z;
  const int tid = threadIdx.x, lane = tid & 63, wave = tid >> 6;
  const int g = lane >> 4, lr = lane & 15;
  const int h = hh >> 1;
  const size_t bT = (size_t)b * T_LEN;

  __shared__ unsigned short Ks[2][64 * 64];
  __shared__ unsigned short Vt[2][128 * 64];
  __shared__ unsigned short Pl[128 * 64];

  const unsigned short* Kbase = Km + bT * E_DIM + hh * HD;
  const unsigned short* Vbase = VT + (size_t)(h * VD) * M_ROWS + b * T_LEN;

#pragma unroll 1
  for (int half = 0; half < 2; ++half) {
    const int qt = half ? (NQT - 1 - pr) : pr;
    const int qbase = qt * 128;
    const int rw0 = qbase + wave * 32;

    // Q fragments in registers
    bf16x8 qf[2][2];
#pragma unroll
    for (int mi = 0; mi < 2; ++mi)
#pragma unroll
      for (int kc = 0; kc < 2; ++kc) {
        const int row = qbase + wave * 32 + mi * 16 + lr;
        qf[mi][kc] = *(const bf16x8*)(Q + (bT + row) * E_DIM + hh * HD + kc * 32 + g * 8);
      }

    f32x4 Oa[2][8];
#pragma unroll
    for (int mi = 0; mi < 2; ++mi)
#pragma unroll
      for (int dv = 0; dv < 8; ++dv) Oa[mi][dv] = (f32x4){0.f, 0.f, 0.f, 0.f};
    float m_run[2][4], l_part[2][4];
#pragma unroll
    for (int mi = 0; mi < 2; ++mi)
#pragma unroll
      for (int r = 0; r < 4; ++r) { m_run[mi][r] = -1e30f; l_part[mi][r] = 0.f; }

    const int nsteps = 2 * qt + 2;
    __syncthreads();                       // buffers free (prev half done)
    stage_kv(Kbase, Vbase, 0, Ks[0], Vt[0], tid, wave);
    int cb = 0;

    for (int ti = 0; ti < nsteps; ++ti) {
      const int s0 = ti * 64;
      __syncthreads();                     // drains staging loads of buf cb
      if (ti + 1 < nsteps)
        stage_kv(Kbase, Vbase, s0 + 64, Ks[cb ^ 1], Vt[cb ^ 1], tid, wave);

      if (s0 <= rw0 + 31) {                // wave-uniform: this wave has rows in range
        const unsigned short* ks = Ks[cb];
        const unsigned short* vt = Vt[cb];
        // ---- QK^T ----
        bf16x8 kb[4][2];
#pragma unroll
        for (int nj = 0; nj < 4; ++nj)
#pragma unroll
          for (int kc = 0; kc < 2; ++kc) {
            const int srow = nj * 16 + lr;
            kb[nj][kc] = *(const bf16x8*)(&ks[srow * 64 + (((kc * 4 + g) ^ (srow & 7)) * 8)]);
          }
        f32x4 Sa[2][4];
#pragma unroll
        for (int mi = 0; mi < 2; ++mi)
#pragma unroll
          for (int nj = 0; nj < 4; ++nj) {
            f32x4 acc = (f32x4){0.f, 0.f, 0.f, 0.f};
#pragma unroll
            for (int kc = 0; kc < 2; ++kc)
              acc = __builtin_amdgcn_mfma_f32_16x16x32_bf16(qf[mi][kc], kb[nj][kc], acc, 0, 0, 0);
            Sa[mi][nj] = acc;
          }

        // ---- causal mask + online softmax (deferred l reduction) ----
        const bool needmask = (s0 + 63) > rw0;
#pragma unroll
        for (int mi = 0; mi < 2; ++mi) {
#pragma unroll
          for (int r = 0; r < 4; ++r) {
            const int rowq = rw0 + mi * 16 + g * 4 + r;
            float mx = -1e30f;
#pragma unroll
            for (int nj = 0; nj < 4; ++nj) {
              float v = Sa[mi][nj][r];
              if (needmask && (s0 + nj * 16 + lr > rowq)) v = -1e30f;
              Sa[mi][nj][r] = v;
              mx = fmaxf(mx, v);
            }
            mx = fmaxf(mx, __shfl_xor(mx, 1));
            mx = fmaxf(mx, __shfl_xor(mx, 2));
            mx = fmaxf(mx, __shfl_xor(mx, 4));
            mx = fmaxf(mx, __shfl_xor(mx, 8));
            const float mn = fmaxf(m_run[mi][r], mx);
            const float rs = __expf(m_run[mi][r] - mn);
            m_run[mi][r] = mn;
            float ps = 0.f;
#pragma unroll
            for (int nj = 0; nj < 4; ++nj) {
              const float p = __expf(Sa[mi][nj][r] - mn);
              Sa[mi][nj][r] = p;
              ps += p;
            }
            l_part[mi][r] = l_part[mi][r] * rs + ps;   // per-lane partial
#pragma unroll
            for (int dv = 0; dv < 8; ++dv) Oa[mi][dv][r] *= rs;
          }
          // write P (bf16) into wave-private LDS rows
#pragma unroll
          for (int nj = 0; nj < 4; ++nj)
#pragma unroll
            for (int r = 0; r < 4; ++r) {
              const int row = wave * 32 + mi * 16 + g * 4 + r;
              const int chunk = (nj * 2 + (lr >> 3)) ^ (row & 7);
              Pl[row * 64 + chunk * 8 + (lr & 7)] = f2bf(Sa[mi][nj][r]);
            }
        }

        // ---- PV ----
        bf16x8 pa[2][2];
#pragma unroll
        for (int mi = 0; mi < 2; ++mi)
#pragma unroll
          for (int kc = 0; kc < 2; ++kc) {
            const int row = wave * 32 + mi * 16 + lr;
            pa[mi][kc] = *(const bf16x8*)(&Pl[row * 64 + (((kc * 4 + g) ^ (row & 7)) * 8)]);
          }
#pragma unroll
        for (int dv = 0; dv < 8; ++dv) {
          bf16x8 vb[2];
#pragma unroll
          for (int kc = 0; kc < 2; ++kc) {
            const int d = dv * 16 + lr;
            vb[kc] = *(const bf16x8*)(&vt[d * 64 + (((kc * 4 + g) ^ (d & 7)) * 8)]);
          }
#pragma unroll
          for (int mi = 0; mi < 2; ++mi)
#pragma unroll
            for (int kc = 0; kc < 2; ++kc)
              Oa[mi][dv] = __builtin_amdgcn_mfma_f32_16x16x32_bf16(pa[mi][kc], vb[kc],
                                                                   Oa[mi][dv], 0, 0, 0);
        }
      }
      cb ^= 1;
    }

    // ---- epilogue: reduce l, normalize, store ----
#pragma unroll
    for (int mi = 0; mi < 2; ++mi)
#pragma unroll
      for (int r = 0; r < 4; ++r) {
        float ls = l_part[mi][r];
        ls += __shfl_xor(ls, 1);
        ls += __shfl_xor(ls, 2);
        ls += __shfl_xor(ls, 4);
        ls += __shfl_xor(ls, 8);
        const float rn = 1.f / ls;
        const int t = qbase + wave * 32 + mi * 16 + g * 4 + r;
        float* orow = Ohalf + ((size_t)(b * HH + hh) * T_LEN + t) * VD;
#pragma unroll
        for (int dv = 0; dv < 8; ++dv)
          orow[dv * 16 + lr] = Oa[mi][dv][r] * rn;
      }
  }
}

// ---------------- differential combine + RMSNorm -> act bf16 [B*T, E] --------
__global__ __launch_bounds__(64) void combine_norm(
    const float* __restrict__ Oh,
    const float* __restrict__ lq1, const float* __restrict__ lk1,
    const float* __restrict__ lq2, const float* __restrict__ lk2,
    const float* __restrict__ g,
    unsigned short* __restrict__ Act) {
  const int lane = threadIdx.x;
  const int r = blockIdx.x;          // (b*T + t)*NH + h
  const int hd = r & 15;
  const int t = (r >> 4) & 2047;
  const int b = r >> 15;
  float p1 = lq1[lane] * lk1[lane];
  float p2 = lq2[lane] * lk2[lane];
#pragma unroll
  for (int o = 1; o < 64; o <<= 1) { p1 += __shfl_xor(p1, o); p2 += __shfl_xor(p2, o); }
  const float lam = __expf(p1) - __expf(p2) + LAMBDA_INIT_F;
  const float* o0 = Oh + ((size_t)(b * HH + 2 * hd) * T_LEN + t) * VD;
  const float* o1 = o0 + (size_t)T_LEN * VD;
  const float x0 = o0[lane]      - lam * o1[lane];
  const float x1 = o0[lane + 64] - lam * o1[lane + 64];
  float ss = x0 * x0 + x1 * x1;
#pragma unroll
  for (int o = 1; o < 64; o <<= 1) ss += __shfl_xor(ss, o);
  const float s = rsqrtf(ss * (1.f / 128.f) + 1e-5f) * ONE_MINUS_LI;
  unsigned short* arow = Act + ((size_t)(b * T_LEN + t) * E_DIM + hd * VD);
  arow[lane]      = f2bf(x0 * s * g[lane]);
  arow[lane + 64] = f2bf(x1 * s * g[lane + 64]);
}

extern "C" void kernel_launch(void* const* d_in, const int* in_sizes, int n_in,
                              void* d_out, int out_size, void* d_ws, size_t ws_size,
                              hipStream_t stream) {
  (void)in_sizes; (void)n_in; (void)out_size; (void)ws_size;
  const float* x   = (const float*)d_in[0];
  const float* Wq  = (const float*)d_in[1];
  const float* Wk  = (const float*)d_in[2];
  const float* Wv  = (const float*)d_in[3];
  const float* Wo  = (const float*)d_in[4];
  const float* lq1 = (const float*)d_in[5];
  const float* lk1 = (const float*)d_in[6];
  const float* lq2 = (const float*)d_in[7];
  const float* lk2 = (const float*)d_in[8];
  const float* g   = (const float*)d_in[9];

  char* p = (char*)d_ws;
  unsigned short* XBF = (unsigned short*)p; p += (size_t)M_ROWS * E_DIM * 2;
  unsigned short* WQB = (unsigned short*)p; p += (size_t)E_DIM * E_DIM * 2;
  unsigned short* WKB = (unsigned short*)p; p += (size_t)E_DIM * E_DIM * 2;
  unsigned short* WVB = (unsigned short*)p; p += (size_t)E_DIM * E_DIM * 2;
  unsigned short* WOB = (unsigned short*)p; p += (size_t)E_DIM * E_DIM * 2;
  unsigned short* QB  = (unsigned short*)p; p += (size_t)M_ROWS * E_DIM * 2;
  unsigned short* KB  = (unsigned short*)p; p += (size_t)M_ROWS * E_DIM * 2;
  unsigned short* VTB = (unsigned short*)p; p += (size_t)M_ROWS * E_DIM * 2;
  float*          OH  = (float*)p;          p += (size_t)B_SZ * HH * T_LEN * VD * 4;
  unsigned short* ACT = (unsigned short*)p; p += (size_t)M_ROWS * E_DIM * 2;

  cast_bf16<<<2048, 256, 0, stream>>>(x,  XBF, M_ROWS * E_DIM / 4);
  cast_bf16<<<1024, 256, 0, stream>>>(Wq, WQB, E_DIM * E_DIM / 4);
  cast_bf16<<<1024, 256, 0, stream>>>(Wk, WKB, E_DIM * E_DIM / 4);
  cast_bf16<<<1024, 256, 0, stream>>>(Wv, WVB, E_DIM * E_DIM / 4);
  cast_bf16<<<1024, 256, 0, stream>>>(Wo, WOB, E_DIM * E_DIM / 4);

  dim3 gg(M_ROWS / 128, E_DIM / 128);
  gemm_bt<0><<<gg, 256, 0, stream>>>(XBF, WQB, QB, M_ROWS, E_DIM, E_DIM, 0.125f); // q * D^-0.5
  gemm_bt<0><<<gg, 256, 0, stream>>>(XBF, WKB, KB, M_ROWS, E_DIM, E_DIM, 1.0f);
  // V^T = Wv * X^T  (operand swap -> coalesced transposed output [E, M_ROWS])
  dim3 gt(E_DIM / 128, M_ROWS / 128);
  gemm_bt<0><<<gt, 256, 0, stream>>>(WVB, XBF, VTB, E_DIM, M_ROWS, E_DIM, 1.0f);

  flash_attn_mfma<<<dim3(NQT / 2, HH, B_SZ), 256, 0, stream>>>(QB, KB, VTB, OH);

  combine_norm<<<B_SZ * T_LEN * NH, 64, 0, stream>>>(OH, lq1, lk1, lq2, lk2, g, ACT);

  gemm_bt<1><<<gg, 256, 0, stream>>>(ACT, WOB, d_out, M_ROWS, E_DIM, E_DIM, 1.0f);
}

// Round 6
// 473.855 us; speedup vs baseline: 7.1241x; 1.0991x over previous
//
#include <hip/hip_runtime.h>

// MultiheadDiffAttn on MI355X — round 5 (resubmit after broker timeout):
// BK=64 GEMM (conflict-free swizzle), merged Q+K projection (N=4096),
// flash softmax VALU trim (truncated-P bf16, exact defer-max skip),
// 4-row combine_norm.

#define B_SZ   2
#define T_LEN  2048
#define E_DIM  2048
#define M_ROWS 4096       // B*T
#define NH     16
#define HH     32         // 2*NH half-heads
#define HD     64         // qk head dim
#define VD     128        // v head dim
#define NQT    16         // T_LEN/128 q-tiles
#define QKLD   4096       // row stride of merged QK buffer

#define LAMBDA_INIT_F 0.7836057665316239f
#define ONE_MINUS_LI  0.2163942334683761f

typedef __attribute__((ext_vector_type(4))) float          f32x4;
typedef __attribute__((ext_vector_type(8))) short          s16x8;
typedef __attribute__((ext_vector_type(4))) unsigned short u16x4;
typedef __attribute__((ext_vector_type(8))) __bf16         bf16x8;

typedef const __attribute__((address_space(1))) unsigned int* gas_t;
typedef __attribute__((address_space(3))) unsigned int*       las_t;
// async global->LDS, 16B per lane; LDS dest = wave-uniform base + lane*16.
__device__ __forceinline__ void gl_lds16(const void* g, void* l) {
  __builtin_amdgcn_global_load_lds((gas_t)g, (las_t)l, 16, 0, 0);
}

__device__ __forceinline__ float bf2f(unsigned short h) {
  union { unsigned u; float f; } v; v.u = ((unsigned)h) << 16; return v.f;
}
__device__ __forceinline__ unsigned short f2bf(float f) {
  union { float f; unsigned u; } v; v.f = f;
  return (unsigned short)((v.u + 0x7fffu + ((v.u >> 16) & 1u)) >> 16);  // RNE
}
__device__ __forceinline__ unsigned fbits(float f) {
  union { float f; unsigned u; } v; v.f = f; return v.u;
}
__device__ __forceinline__ float bits2f(unsigned u) {
  union { unsigned u; float f; } v; v.u = u; return v.f;
}

// ---------------- cast f32 -> bf16 (scaled), float4-vectorized ----------------
__global__ __launch_bounds__(256) void cast_bf16(const float* __restrict__ in,
                                                 unsigned short* __restrict__ out,
                                                 int n4, float scale) {
  int i = blockIdx.x * 256 + threadIdx.x;
  const int stride = gridDim.x * 256;
  for (; i < n4; i += stride) {
    f32x4 v = ((const f32x4*)in)[i];
    u16x4 o;
    o[0] = f2bf(v[0] * scale); o[1] = f2bf(v[1] * scale);
    o[2] = f2bf(v[2] * scale); o[3] = f2bf(v[3] * scale);
    ((u16x4*)out)[i] = o;
  }
}

// ---------------- GEMM: C[M,N] = A(bf16 [M,K]) * B(bf16 [N,K])^T --------------
// 128x128 tile, BK=64, 4 waves. global_load_lds staging into linear LDS;
// source pre-swizzled chunk ^= row&7 (128B rows -> 2-way bank access = free).
template <int OUT_F32>
__global__ __launch_bounds__(256) void gemm_bt(const unsigned short* __restrict__ A,
                                               const unsigned short* __restrict__ Bm,
                                               void* __restrict__ Cout,
                                               int M, int N, int K, float alpha) {
  __shared__ unsigned short As[128 * 64];
  __shared__ unsigned short Bs[128 * 64];
  const int tid  = threadIdx.x;
  const int lane = tid & 63;
  const int wave = tid >> 6;
  const int wr = wave >> 1, wc = wave & 1;
  const int lrow = lane & 15, lkb = lane >> 4;
  const int m0 = blockIdx.x * 128, n0 = blockIdx.y * 128;

  f32x4 acc[4][4] = {};

  for (int k0 = 0; k0 < K; k0 += 64) {
#pragma unroll
    for (int it = 0; it < 4; ++it) {
      const int ci  = tid + it * 256;          // 0..1023 chunk ids
      const int row = ci >> 3;
      const int cs  = (ci & 7) ^ (row & 7);    // pre-swizzled source chunk
      const int rb  = (wave * 64 + it * 256) * 8;  // wave-uniform LDS base (elems)
      gl_lds16(A  + (size_t)(m0 + row) * K + k0 + cs * 8, &As[rb]);
      gl_lds16(Bm + (size_t)(n0 + row) * K + k0 + cs * 8, &Bs[rb]);
    }
    __syncthreads();
    bf16x8 af[4][2], bfr[4][2];
#pragma unroll
    for (int mi = 0; mi < 4; ++mi) {
      const int r = wr * 64 + mi * 16 + lrow;
#pragma unroll
      for (int kc = 0; kc < 2; ++kc)
        af[mi][kc] = *(const bf16x8*)(&As[r * 64 + (((kc * 4 + lkb) ^ (r & 7)) * 8)]);
    }
#pragma unroll
    for (int ni = 0; ni < 4; ++ni) {
      const int r = wc * 64 + ni * 16 + lrow;
#pragma unroll
      for (int kc = 0; kc < 2; ++kc)
        bfr[ni][kc] = *(const bf16x8*)(&Bs[r * 64 + (((kc * 4 + lkb) ^ (r & 7)) * 8)]);
    }
#pragma unroll
    for (int mi = 0; mi < 4; ++mi)
#pragma unroll
      for (int ni = 0; ni < 4; ++ni)
#pragma unroll
        for (int kc = 0; kc < 2; ++kc)
          acc[mi][ni] = __builtin_amdgcn_mfma_f32_16x16x32_bf16(af[mi][kc], bfr[ni][kc],
                                                                acc[mi][ni], 0, 0, 0);
    __syncthreads();
  }
#pragma unroll
  for (int mi = 0; mi < 4; ++mi) {
#pragma unroll
    for (int ni = 0; ni < 4; ++ni) {
      const int mb = m0 + wr * 64 + mi * 16 + lkb * 4;
      const int nn = n0 + wc * 64 + ni * 16 + lrow;
#pragma unroll
      for (int r = 0; r < 4; ++r) {
        const float v = acc[mi][ni][r] * alpha;
        const size_t idx = (size_t)(mb + r) * N + nn;
        if (OUT_F32) ((float*)Cout)[idx] = v;
        else         ((unsigned short*)Cout)[idx] = f2bf(v);
      }
    }
  }
}

// ---------------- MFMA flash attention (paired tiles, async dbuf staging) ----
// Block = 4 waves, q-tiles {pr, 15-pr} of one (b, half-head): 34 KV-steps.
// Q/K come from merged QK buffer [M_ROWS][QKLD] (Q cols 0..2047, K cols 2048+).
__device__ __forceinline__ void stage_kv(const unsigned short* __restrict__ Kbase,
                                         const unsigned short* __restrict__ Vbase,
                                         int s0, unsigned short* KsBuf,
                                         unsigned short* VtBuf, int tid, int wave) {
#pragma unroll
  for (int j = 0; j < 2; ++j) {       // K: 64 rows x 64 elems
    const int ci = tid + j * 256;
    const int s = ci >> 3;
    const int cs = (ci & 7) ^ (s & 7);
    gl_lds16(Kbase + (size_t)(s0 + s) * QKLD + cs * 8, KsBuf + (wave * 64 + j * 256) * 8);
  }
#pragma unroll
  for (int cc = 0; cc < 4; ++cc) {    // V^T: 128 rows x 64 elems
    const int ci = tid + cc * 256;
    const int d = ci >> 3;
    const int cs = (ci & 7) ^ (d & 7);
    gl_lds16(Vbase + (size_t)d * M_ROWS + s0 + cs * 8, VtBuf + (wave * 64 + cc * 256) * 8);
  }
}

__global__ __launch_bounds__(256, 2) void flash_attn_mfma(
    const unsigned short* __restrict__ QK,  // [B*T, QKLD] bf16 (Q pre-scaled)
    const unsigned short* __restrict__ VT,  // [E, B*T] bf16 (V transposed)
    float* __restrict__ Ohalf) {            // [B, HH, T, VD] f32
  const int pr = blockIdx.x;                // pair 0..7
  const int hh = blockIdx.y;
  const int b  = blockIdx.z;
  const int tid = threadIdx.x, lane = tid & 63, wave = tid >> 6;
  const int g = lane >> 4, lr = lane & 15;
  const int h = hh >> 1;
  const size_t bT = (size_t)b * T_LEN;

  __shared__ unsigned short Ks[2][64 * 64];
  __shared__ unsigned short Vt[2][128 * 64];
  __shared__ unsigned short Pl[128 * 64];

  const unsigned short* Kbase = QK + bT * QKLD + E_DIM + hh * HD;   // K half
  const unsigned short* Vbase = VT + (size_t)(h * VD) * M_ROWS + b * T_LEN;

#pragma unroll 1
  for (int half = 0; half < 2; ++half) {
    const int qt = half ? (NQT - 1 - pr) : pr;
    const int qbase = qt * 128;
    const int rw0 = qbase + wave * 32;

    // Q fragments in registers
    bf16x8 qf[2][2];
#pragma unroll
    for (int mi = 0; mi < 2; ++mi)
#pragma unroll
      for (int kc = 0; kc < 2; ++kc) {
        const int row = qbase + wave * 32 + mi * 16 + lr;
        qf[mi][kc] = *(const bf16x8*)(QK + (bT + row) * QKLD + hh * HD + kc * 32 + g * 8);
      }

    f32x4 Oa[2][8];
#pragma unroll
    for (int mi = 0; mi < 2; ++mi)
#pragma unroll
      for (int dv = 0; dv < 8; ++dv) Oa[mi][dv] = (f32x4){0.f, 0.f, 0.f, 0.f};
    float m_run[2][4], l_part[2][4];
#pragma unroll
    for (int mi = 0; mi < 2; ++mi)
#pragma unroll
      for (int r = 0; r < 4; ++r) { m_run[mi][r] = -1e30f; l_part[mi][r] = 0.f; }

    const int nsteps = 2 * qt + 2;
    __syncthreads();                       // buffers free (prev half done)
    stage_kv(Kbase, Vbase, 0, Ks[0], Vt[0], tid, wave);
    int cb = 0;

    for (int ti = 0; ti < nsteps; ++ti) {
      const int s0 = ti * 64;
      __syncthreads();                     // drains staging loads of buf cb
      if (ti + 1 < nsteps)
        stage_kv(Kbase, Vbase, s0 + 64, Ks[cb ^ 1], Vt[cb ^ 1], tid, wave);

      if (s0 <= rw0 + 31) {                // wave-uniform guard
        const unsigned short* ks = Ks[cb];
        const unsigned short* vt = Vt[cb];
        // ---- QK^T ----
        bf16x8 kb[4][2];
#pragma unroll
        for (int nj = 0; nj < 4; ++nj)
#pragma unroll
          for (int kc = 0; kc < 2; ++kc) {
            const int srow = nj * 16 + lr;
            kb[nj][kc] = *(const bf16x8*)(&ks[srow * 64 + (((kc * 4 + g) ^ (srow & 7)) * 8)]);
          }
        f32x4 Sa[2][4];
#pragma unroll
        for (int mi = 0; mi < 2; ++mi)
#pragma unroll
          for (int nj = 0; nj < 4; ++nj) {
            f32x4 acc = (f32x4){0.f, 0.f, 0.f, 0.f};
#pragma unroll
            for (int kc = 0; kc < 2; ++kc)
              acc = __builtin_amdgcn_mfma_f32_16x16x32_bf16(qf[mi][kc], kb[nj][kc], acc, 0, 0, 0);
            Sa[mi][nj] = acc;
          }

        // ---- causal mask + row maxima ----
        const bool needmask = (s0 + 63) > rw0;
        float mx[2][4];
        bool anew = false;
#pragma unroll
        for (int mi = 0; mi < 2; ++mi)
#pragma unroll
          for (int r = 0; r < 4; ++r) {
            const int rowq = rw0 + mi * 16 + g * 4 + r;
            float m0v = -1e30f;
#pragma unroll
            for (int nj = 0; nj < 4; ++nj) {
              float v = Sa[mi][nj][r];
              if (needmask && (s0 + nj * 16 + lr > rowq)) v = -1e30f;
              Sa[mi][nj][r] = v;
              m0v = fmaxf(m0v, v);
            }
            m0v = fmaxf(m0v, __shfl_xor(m0v, 1));
            m0v = fmaxf(m0v, __shfl_xor(m0v, 2));
            m0v = fmaxf(m0v, __shfl_xor(m0v, 4));
            m0v = fmaxf(m0v, __shfl_xor(m0v, 8));
            mx[mi][r] = m0v;
            anew |= (m0v > m_run[mi][r]);
          }

        // ---- rescale only when some row has a new max (exact skip) ----
        if (__any(anew)) {
#pragma unroll
          for (int mi = 0; mi < 2; ++mi)
#pragma unroll
            for (int r = 0; r < 4; ++r) {
              const float mn = fmaxf(m_run[mi][r], mx[mi][r]);
              const float rs = __expf(m_run[mi][r] - mn);
              m_run[mi][r] = mn;
              l_part[mi][r] *= rs;
#pragma unroll
              for (int dv = 0; dv < 8; ++dv) Oa[mi][dv][r] *= rs;
            }
        }

        // ---- exp, truncate-to-bf16 P (consistent l), store to LDS ----
#pragma unroll
        for (int mi = 0; mi < 2; ++mi) {
#pragma unroll
          for (int r = 0; r < 4; ++r) {
            const int row = wave * 32 + mi * 16 + g * 4 + r;
            float ps = 0.f;
#pragma unroll
            for (int nj = 0; nj < 4; ++nj) {
              const float p = __expf(Sa[mi][nj][r] - m_run[mi][r]);
              const unsigned u = fbits(p);
              const int chunk = (nj * 2 + (lr >> 3)) ^ (row & 7);
              Pl[row * 64 + chunk * 8 + (lr & 7)] = (unsigned short)(u >> 16);
              ps += bits2f(u & 0xffff0000u);   // sum the truncated values
            }
            l_part[mi][r] += ps;
          }
        }

        // ---- PV ----
        bf16x8 pa[2][2];
#pragma unroll
        for (int mi = 0; mi < 2; ++mi)
#pragma unroll
          for (int kc = 0; kc < 2; ++kc) {
            const int row = wave * 32 + mi * 16 + lr;
            pa[mi][kc] = *(const bf16x8*)(&Pl[row * 64 + (((kc * 4 + g) ^ (row & 7)) * 8)]);
          }
#pragma unroll
        for (int dv = 0; dv < 8; ++dv) {
          bf16x8 vb[2];
#pragma unroll
          for (int kc = 0; kc < 2; ++kc) {
            const int d = dv * 16 + lr;
            vb[kc] = *(const bf16x8*)(&vt[d * 64 + (((kc * 4 + g) ^ (d & 7)) * 8)]);
          }
#pragma unroll
          for (int mi = 0; mi < 2; ++mi)
#pragma unroll
            for (int kc = 0; kc < 2; ++kc)
              Oa[mi][dv] = __builtin_amdgcn_mfma_f32_16x16x32_bf16(pa[mi][kc], vb[kc],
                                                                   Oa[mi][dv], 0, 0, 0);
        }
      }
      cb ^= 1;
    }

    // ---- epilogue: reduce l, normalize, store ----
#pragma unroll
    for (int mi = 0; mi < 2; ++mi)
#pragma unroll
      for (int r = 0; r < 4; ++r) {
        float ls = l_part[mi][r];
        ls += __shfl_xor(ls, 1);
        ls += __shfl_xor(ls, 2);
        ls += __shfl_xor(ls, 4);
        ls += __shfl_xor(ls, 8);
        const float rn = 1.f / ls;
        const int t = qbase + wave * 32 + mi * 16 + g * 4 + r;
        float* orow = Ohalf + ((size_t)(b * HH + hh) * T_LEN + t) * VD;
#pragma unroll
        for (int dv = 0; dv < 8; ++dv)
          orow[dv * 16 + lr] = Oa[mi][dv][r] * rn;
      }
  }
}

// ---------------- differential combine + RMSNorm -> act bf16 [B*T, E] --------
// 256 threads = 4 waves, each wave one (b,t,h) row.
__global__ __launch_bounds__(256) void combine_norm(
    const float* __restrict__ Oh,
    const float* __restrict__ lq1, const float* __restrict__ lk1,
    const float* __restrict__ lq2, const float* __restrict__ lk2,
    const float* __restrict__ g,
    unsigned short* __restrict__ Act) {
  const int lane = threadIdx.x & 63;
  const int r = blockIdx.x * 4 + (threadIdx.x >> 6);   // (b*T + t)*NH + h
  const int hd = r & 15;
  const int t = (r >> 4) & 2047;
  const int b = r >> 15;
  float p1 = lq1[lane] * lk1[lane];
  float p2 = lq2[lane] * lk2[lane];
#pragma unroll
  for (int o = 1; o < 64; o <<= 1) { p1 += __shfl_xor(p1, o); p2 += __shfl_xor(p2, o); }
  const float lam = __expf(p1) - __expf(p2) + LAMBDA_INIT_F;
  const float* o0 = Oh + ((size_t)(b * HH + 2 * hd) * T_LEN + t) * VD;
  const float* o1 = o0 + (size_t)T_LEN * VD;
  const float x0 = o0[lane]      - lam * o1[lane];
  const float x1 = o0[lane + 64] - lam * o1[lane + 64];
  float ss = x0 * x0 + x1 * x1;
#pragma unroll
  for (int o = 1; o < 64; o <<= 1) ss += __shfl_xor(ss, o);
  const float s = rsqrtf(ss * (1.f / 128.f) + 1e-5f) * ONE_MINUS_LI;
  unsigned short* arow = Act + ((size_t)(b * T_LEN + t) * E_DIM + hd * VD);
  arow[lane]      = f2bf(x0 * s * g[lane]);
  arow[lane + 64] = f2bf(x1 * s * g[lane + 64]);
}

extern "C" void kernel_launch(void* const* d_in, const int* in_sizes, int n_in,
                              void* d_out, int out_size, void* d_ws, size_t ws_size,
                              hipStream_t stream) {
  (void)in_sizes; (void)n_in; (void)out_size; (void)ws_size;
  const float* x   = (const float*)d_in[0];
  const float* Wq  = (const float*)d_in[1];
  const float* Wk  = (const float*)d_in[2];
  const float* Wv  = (const float*)d_in[3];
  const float* Wo  = (const float*)d_in[4];
  const float* lq1 = (const float*)d_in[5];
  const float* lk1 = (const float*)d_in[6];
  const float* lq2 = (const float*)d_in[7];
  const float* lk2 = (const float*)d_in[8];
  const float* g   = (const float*)d_in[9];

  char* p = (char*)d_ws;
  unsigned short* XBF = (unsigned short*)p; p += (size_t)M_ROWS * E_DIM * 2;
  unsigned short* WQB = (unsigned short*)p; p += (size_t)E_DIM * E_DIM * 2;  // Wq (scaled)
  unsigned short* WKB = (unsigned short*)p; p += (size_t)E_DIM * E_DIM * 2;  // Wk (adjacent!)
  unsigned short* WVB = (unsigned short*)p; p += (size_t)E_DIM * E_DIM * 2;
  unsigned short* WOB = (unsigned short*)p; p += (size_t)E_DIM * E_DIM * 2;
  unsigned short* QKB = (unsigned short*)p; p += (size_t)M_ROWS * QKLD * 2;  // merged Q|K
  unsigned short* VTB = (unsigned short*)p; p += (size_t)M_ROWS * E_DIM * 2;
  float*          OH  = (float*)p;          p += (size_t)B_SZ * HH * T_LEN * VD * 4;
  unsigned short* ACT = (unsigned short*)p; p += (size_t)M_ROWS * E_DIM * 2;

  cast_bf16<<<2048, 256, 0, stream>>>(x,  XBF, M_ROWS * E_DIM / 4, 1.0f);
  cast_bf16<<<1024, 256, 0, stream>>>(Wq, WQB, E_DIM * E_DIM / 4, 0.125f);  // fold D^-0.5
  cast_bf16<<<1024, 256, 0, stream>>>(Wk, WKB, E_DIM * E_DIM / 4, 1.0f);
  cast_bf16<<<1024, 256, 0, stream>>>(Wv, WVB, E_DIM * E_DIM / 4, 1.0f);
  cast_bf16<<<1024, 256, 0, stream>>>(Wo, WOB, E_DIM * E_DIM / 4, 1.0f);

  // merged Q|K projection: B = stacked [WQB; WKB] (contiguous), N = 4096
  dim3 gqk(M_ROWS / 128, (2 * E_DIM) / 128);
  gemm_bt<0><<<gqk, 256, 0, stream>>>(XBF, WQB, QKB, M_ROWS, 2 * E_DIM, E_DIM, 1.0f);
  // V^T = Wv * X^T  (operand swap -> coalesced transposed output [E, M_ROWS])
  dim3 gt(E_DIM / 128, M_ROWS / 128);
  gemm_bt<0><<<gt, 256, 0, stream>>>(WVB, XBF, VTB, E_DIM, M_ROWS, E_DIM, 1.0f);

  flash_attn_mfma<<<dim3(NQT / 2, HH, B_SZ), 256, 0, stream>>>(QKB, VTB, OH);

  combine_norm<<<B_SZ * T_LEN * NH / 4, 256, 0, stream>>>(OH, lq1, lk1, lq2, lk2, g, ACT);

  dim3 gg(M_ROWS / 128, E_DIM / 128);
  gemm_bt<1><<<gg, 256, 0, stream>>>(ACT, WOB, d_out, M_ROWS, E_DIM, E_DIM, 1.0f);
}

// Round 7
// 420.072 us; speedup vs baseline: 8.0362x; 1.1280x over previous
//
#include <hip/hip_runtime.h>

// MultiheadDiffAttn on MI355X — round 7: GEMM occupancy fix (kc-outer frags,
// launch_bounds 256x3) + flash T13 defer-max threshold.

#define B_SZ   2
#define T_LEN  2048
#define E_DIM  2048
#define M_ROWS 4096       // B*T
#define NH     16
#define HH     32         // 2*NH half-heads
#define HD     64         // qk head dim
#define VD     128        // v head dim
#define NQT    16         // T_LEN/128 q-tiles
#define QKLD   4096       // row stride of merged QK buffer

#define LAMBDA_INIT_F 0.7836057665316239f
#define ONE_MINUS_LI  0.2163942334683761f

typedef __attribute__((ext_vector_type(4))) float          f32x4;
typedef __attribute__((ext_vector_type(8))) short          s16x8;
typedef __attribute__((ext_vector_type(4))) unsigned short u16x4;
typedef __attribute__((ext_vector_type(8))) __bf16         bf16x8;

typedef const __attribute__((address_space(1))) unsigned int* gas_t;
typedef __attribute__((address_space(3))) unsigned int*       las_t;
// async global->LDS, 16B per lane; LDS dest = wave-uniform base + lane*16.
__device__ __forceinline__ void gl_lds16(const void* g, void* l) {
  __builtin_amdgcn_global_load_lds((gas_t)g, (las_t)l, 16, 0, 0);
}

__device__ __forceinline__ float bf2f(unsigned short h) {
  union { unsigned u; float f; } v; v.u = ((unsigned)h) << 16; return v.f;
}
__device__ __forceinline__ unsigned short f2bf(float f) {
  union { float f; unsigned u; } v; v.f = f;
  return (unsigned short)((v.u + 0x7fffu + ((v.u >> 16) & 1u)) >> 16);  // RNE
}
__device__ __forceinline__ unsigned fbits(float f) {
  union { float f; unsigned u; } v; v.f = f; return v.u;
}
__device__ __forceinline__ float bits2f(unsigned u) {
  union { unsigned u; float f; } v; v.u = u; return v.f;
}

// ---------------- cast f32 -> bf16 (scaled), float4-vectorized ----------------
__global__ __launch_bounds__(256) void cast_bf16(const float* __restrict__ in,
                                                 unsigned short* __restrict__ out,
                                                 int n4, float scale) {
  int i = blockIdx.x * 256 + threadIdx.x;
  const int stride = gridDim.x * 256;
  for (; i < n4; i += stride) {
    f32x4 v = ((const f32x4*)in)[i];
    u16x4 o;
    o[0] = f2bf(v[0] * scale); o[1] = f2bf(v[1] * scale);
    o[2] = f2bf(v[2] * scale); o[3] = f2bf(v[3] * scale);
    ((u16x4*)out)[i] = o;
  }
}

// ---------------- GEMM: C[M,N] = A(bf16 [M,K]) * B(bf16 [N,K])^T --------------
// 128x128 tile, BK=64, 4 waves, 3 blocks/CU. kc-outer fragment reads keep
// frag regs at 32 (acc 64) so launch_bounds(256,3) fits without spill.
template <int OUT_F32>
__global__ __launch_bounds__(256, 3) void gemm_bt(const unsigned short* __restrict__ A,
                                                  const unsigned short* __restrict__ Bm,
                                                  void* __restrict__ Cout,
                                                  int M, int N, int K, float alpha) {
  __shared__ unsigned short As[128 * 64];
  __shared__ unsigned short Bs[128 * 64];
  const int tid  = threadIdx.x;
  const int lane = tid & 63;
  const int wave = tid >> 6;
  const int wr = wave >> 1, wc = wave & 1;
  const int lrow = lane & 15, lkb = lane >> 4;
  const int m0 = blockIdx.x * 128, n0 = blockIdx.y * 128;

  f32x4 acc[4][4] = {};

  for (int k0 = 0; k0 < K; k0 += 64) {
#pragma unroll
    for (int it = 0; it < 4; ++it) {
      const int ci  = tid + it * 256;          // 0..1023 chunk ids
      const int row = ci >> 3;
      const int cs  = (ci & 7) ^ (row & 7);    // pre-swizzled source chunk
      const int rb  = (wave * 64 + it * 256) * 8;  // wave-uniform LDS base (elems)
      gl_lds16(A  + (size_t)(m0 + row) * K + k0 + cs * 8, &As[rb]);
      gl_lds16(Bm + (size_t)(n0 + row) * K + k0 + cs * 8, &Bs[rb]);
    }
    __syncthreads();
#pragma unroll
    for (int kc = 0; kc < 2; ++kc) {
      bf16x8 af[4], bfr[4];
#pragma unroll
      for (int mi = 0; mi < 4; ++mi) {
        const int r = wr * 64 + mi * 16 + lrow;
        af[mi] = *(const bf16x8*)(&As[r * 64 + (((kc * 4 + lkb) ^ (r & 7)) * 8)]);
      }
#pragma unroll
      for (int ni = 0; ni < 4; ++ni) {
        const int r = wc * 64 + ni * 16 + lrow;
        bfr[ni] = *(const bf16x8*)(&Bs[r * 64 + (((kc * 4 + lkb) ^ (r & 7)) * 8)]);
      }
#pragma unroll
      for (int mi = 0; mi < 4; ++mi)
#pragma unroll
        for (int ni = 0; ni < 4; ++ni)
          acc[mi][ni] = __builtin_amdgcn_mfma_f32_16x16x32_bf16(af[mi], bfr[ni],
                                                                acc[mi][ni], 0, 0, 0);
    }
    __syncthreads();
  }
#pragma unroll
  for (int mi = 0; mi < 4; ++mi) {
#pragma unroll
    for (int ni = 0; ni < 4; ++ni) {
      const int mb = m0 + wr * 64 + mi * 16 + lkb * 4;
      const int nn = n0 + wc * 64 + ni * 16 + lrow;
#pragma unroll
      for (int r = 0; r < 4; ++r) {
        const float v = acc[mi][ni][r] * alpha;
        const size_t idx = (size_t)(mb + r) * N + nn;
        if (OUT_F32) ((float*)Cout)[idx] = v;
        else         ((unsigned short*)Cout)[idx] = f2bf(v);
      }
    }
  }
}

// ---------------- MFMA flash attention (paired tiles, async dbuf staging) ----
// Block = 4 waves, q-tiles {pr, 15-pr} of one (b, half-head): 34 KV-steps.
// Q/K come from merged QK buffer [M_ROWS][QKLD] (Q cols 0..2047, K cols 2048+).
__device__ __forceinline__ void stage_kv(const unsigned short* __restrict__ Kbase,
                                         const unsigned short* __restrict__ Vbase,
                                         int s0, unsigned short* KsBuf,
                                         unsigned short* VtBuf, int tid, int wave) {
#pragma unroll
  for (int j = 0; j < 2; ++j) {       // K: 64 rows x 64 elems
    const int ci = tid + j * 256;
    const int s = ci >> 3;
    const int cs = (ci & 7) ^ (s & 7);
    gl_lds16(Kbase + (size_t)(s0 + s) * QKLD + cs * 8, KsBuf + (wave * 64 + j * 256) * 8);
  }
#pragma unroll
  for (int cc = 0; cc < 4; ++cc) {    // V^T: 128 rows x 64 elems
    const int ci = tid + cc * 256;
    const int d = ci >> 3;
    const int cs = (ci & 7) ^ (d & 7);
    gl_lds16(Vbase + (size_t)d * M_ROWS + s0 + cs * 8, VtBuf + (wave * 64 + cc * 256) * 8);
  }
}

__global__ __launch_bounds__(256, 2) void flash_attn_mfma(
    const unsigned short* __restrict__ QK,  // [B*T, QKLD] bf16 (Q pre-scaled)
    const unsigned short* __restrict__ VT,  // [E, B*T] bf16 (V transposed)
    float* __restrict__ Ohalf) {            // [B, HH, T, VD] f32
  const int pr = blockIdx.x;                // pair 0..7
  const int hh = blockIdx.y;
  const int b  = blockIdx.z;
  const int tid = threadIdx.x, lane = tid & 63, wave = tid >> 6;
  const int g = lane >> 4, lr = lane & 15;
  const int h = hh >> 1;
  const size_t bT = (size_t)b * T_LEN;

  __shared__ unsigned short Ks[2][64 * 64];
  __shared__ unsigned short Vt[2][128 * 64];
  __shared__ unsigned short Pl[128 * 64];

  const unsigned short* Kbase = QK + bT * QKLD + E_DIM + hh * HD;   // K half
  const unsigned short* Vbase = VT + (size_t)(h * VD) * M_ROWS + b * T_LEN;

#pragma unroll 1
  for (int half = 0; half < 2; ++half) {
    const int qt = half ? (NQT - 1 - pr) : pr;
    const int qbase = qt * 128;
    const int rw0 = qbase + wave * 32;

    // Q fragments in registers
    bf16x8 qf[2][2];
#pragma unroll
    for (int mi = 0; mi < 2; ++mi)
#pragma unroll
      for (int kc = 0; kc < 2; ++kc) {
        const int row = qbase + wave * 32 + mi * 16 + lr;
        qf[mi][kc] = *(const bf16x8*)(QK + (bT + row) * QKLD + hh * HD + kc * 32 + g * 8);
      }

    f32x4 Oa[2][8];
#pragma unroll
    for (int mi = 0; mi < 2; ++mi)
#pragma unroll
      for (int dv = 0; dv < 8; ++dv) Oa[mi][dv] = (f32x4){0.f, 0.f, 0.f, 0.f};
    float m_run[2][4], l_part[2][4];
#pragma unroll
    for (int mi = 0; mi < 2; ++mi)
#pragma unroll
      for (int r = 0; r < 4; ++r) { m_run[mi][r] = -1e30f; l_part[mi][r] = 0.f; }

    const int nsteps = 2 * qt + 2;
    __syncthreads();                       // buffers free (prev half done)
    stage_kv(Kbase, Vbase, 0, Ks[0], Vt[0], tid, wave);
    int cb = 0;

    for (int ti = 0; ti < nsteps; ++ti) {
      const int s0 = ti * 64;
      __syncthreads();                     // drains staging loads of buf cb
      if (ti + 1 < nsteps)
        stage_kv(Kbase, Vbase, s0 + 64, Ks[cb ^ 1], Vt[cb ^ 1], tid, wave);

      if (s0 <= rw0 + 31) {                // wave-uniform guard
        const unsigned short* ks = Ks[cb];
        const unsigned short* vt = Vt[cb];
        // ---- QK^T ----
        bf16x8 kb[4][2];
#pragma unroll
        for (int nj = 0; nj < 4; ++nj)
#pragma unroll
          for (int kc = 0; kc < 2; ++kc) {
            const int srow = nj * 16 + lr;
            kb[nj][kc] = *(const bf16x8*)(&ks[srow * 64 + (((kc * 4 + g) ^ (srow & 7)) * 8)]);
          }
        f32x4 Sa[2][4];
#pragma unroll
        for (int mi = 0; mi < 2; ++mi)
#pragma unroll
          for (int nj = 0; nj < 4; ++nj) {
            f32x4 acc = (f32x4){0.f, 0.f, 0.f, 0.f};
#pragma unroll
            for (int kc = 0; kc < 2; ++kc)
              acc = __builtin_amdgcn_mfma_f32_16x16x32_bf16(qf[mi][kc], kb[nj][kc], acc, 0, 0, 0);
            Sa[mi][nj] = acc;
          }

        // ---- causal mask + row maxima ----
        const bool needmask = (s0 + 63) > rw0;
        float mx[2][4];
        bool anew = false;
#pragma unroll
        for (int mi = 0; mi < 2; ++mi)
#pragma unroll
          for (int r = 0; r < 4; ++r) {
            const int rowq = rw0 + mi * 16 + g * 4 + r;
            float m0v = -1e30f;
#pragma unroll
            for (int nj = 0; nj < 4; ++nj) {
              float v = Sa[mi][nj][r];
              if (needmask && (s0 + nj * 16 + lr > rowq)) v = -1e30f;
              Sa[mi][nj][r] = v;
              m0v = fmaxf(m0v, v);
            }
            m0v = fmaxf(m0v, __shfl_xor(m0v, 1));
            m0v = fmaxf(m0v, __shfl_xor(m0v, 2));
            m0v = fmaxf(m0v, __shfl_xor(m0v, 4));
            m0v = fmaxf(m0v, __shfl_xor(m0v, 8));
            mx[mi][r] = m0v;
            anew |= (m0v > m_run[mi][r] + 8.0f);   // T13: defer-max threshold
          }

        // ---- rescale only when some row exceeded threshold (rare) ----
        if (__any(anew)) {
#pragma unroll
          for (int mi = 0; mi < 2; ++mi)
#pragma unroll
            for (int r = 0; r < 4; ++r) {
              const float mn = fmaxf(m_run[mi][r], mx[mi][r]);
              const float rs = __expf(m_run[mi][r] - mn);
              m_run[mi][r] = mn;
              l_part[mi][r] *= rs;
#pragma unroll
              for (int dv = 0; dv < 8; ++dv) Oa[mi][dv][r] *= rs;
            }
        }

        // ---- exp (bounded by e^8), truncate-to-bf16 P, consistent l ----
#pragma unroll
        for (int mi = 0; mi < 2; ++mi) {
#pragma unroll
          for (int r = 0; r < 4; ++r) {
            const int row = wave * 32 + mi * 16 + g * 4 + r;
            float ps = 0.f;
#pragma unroll
            for (int nj = 0; nj < 4; ++nj) {
              const float p = __expf(Sa[mi][nj][r] - m_run[mi][r]);
              const unsigned u = fbits(p);
              const int chunk = (nj * 2 + (lr >> 3)) ^ (row & 7);
              Pl[row * 64 + chunk * 8 + (lr & 7)] = (unsigned short)(u >> 16);
              ps += bits2f(u & 0xffff0000u);   // sum the truncated values
            }
            l_part[mi][r] += ps;
          }
        }

        // ---- PV ----
        bf16x8 pa[2][2];
#pragma unroll
        for (int mi = 0; mi < 2; ++mi)
#pragma unroll
          for (int kc = 0; kc < 2; ++kc) {
            const int row = wave * 32 + mi * 16 + lr;
            pa[mi][kc] = *(const bf16x8*)(&Pl[row * 64 + (((kc * 4 + g) ^ (row & 7)) * 8)]);
          }
#pragma unroll
        for (int dv = 0; dv < 8; ++dv) {
          bf16x8 vb[2];
#pragma unroll
          for (int kc = 0; kc < 2; ++kc) {
            const int d = dv * 16 + lr;
            vb[kc] = *(const bf16x8*)(&vt[d * 64 + (((kc * 4 + g) ^ (d & 7)) * 8)]);
          }
#pragma unroll
          for (int mi = 0; mi < 2; ++mi)
#pragma unroll
            for (int kc = 0; kc < 2; ++kc)
              Oa[mi][dv] = __builtin_amdgcn_mfma_f32_16x16x32_bf16(pa[mi][kc], vb[kc],
                                                                   Oa[mi][dv], 0, 0, 0);
        }
      }
      cb ^= 1;
    }

    // ---- epilogue: reduce l, normalize, store ----
#pragma unroll
    for (int mi = 0; mi < 2; ++mi)
#pragma unroll
      for (int r = 0; r < 4; ++r) {
        float ls = l_part[mi][r];
        ls += __shfl_xor(ls, 1);
        ls += __shfl_xor(ls, 2);
        ls += __shfl_xor(ls, 4);
        ls += __shfl_xor(ls, 8);
        const float rn = 1.f / ls;
        const int t = qbase + wave * 32 + mi * 16 + g * 4 + r;
        float* orow = Ohalf + ((size_t)(b * HH + hh) * T_LEN + t) * VD;
#pragma unroll
        for (int dv = 0; dv < 8; ++dv)
          orow[dv * 16 + lr] = Oa[mi][dv][r] * rn;
      }
  }
}

// ---------------- differential combine + RMSNorm -> act bf16 [B*T, E] --------
// 256 threads = 4 waves, each wave one (b,t,h) row.
__global__ __launch_bounds__(256) void combine_norm(
    const float* __restrict__ Oh,
    const float* __restrict__ lq1, const float* __restrict__ lk1,
    const float* __restrict__ lq2, const float* __restrict__ lk2,
    const float* __restrict__ g,
    unsigned short* __restrict__ Act) {
  const int lane = threadIdx.x & 63;
  const int r = blockIdx.x * 4 + (threadIdx.x >> 6);   // (b*T + t)*NH + h
  const int hd = r & 15;
  const int t = (r >> 4) & 2047;
  const int b = r >> 15;
  float p1 = lq1[lane] * lk1[lane];
  float p2 = lq2[lane] * lk2[lane];
#pragma unroll
  for (int o = 1; o < 64; o <<= 1) { p1 += __shfl_xor(p1, o); p2 += __shfl_xor(p2, o); }
  const float lam = __expf(p1) - __expf(p2) + LAMBDA_INIT_F;
  const float* o0 = Oh + ((size_t)(b * HH + 2 * hd) * T_LEN + t) * VD;
  const float* o1 = o0 + (size_t)T_LEN * VD;
  const float x0 = o0[lane]      - lam * o1[lane];
  const float x1 = o0[lane + 64] - lam * o1[lane + 64];
  float ss = x0 * x0 + x1 * x1;
#pragma unroll
  for (int o = 1; o < 64; o <<= 1) ss += __shfl_xor(ss, o);
  const float s = rsqrtf(ss * (1.f / 128.f) + 1e-5f) * ONE_MINUS_LI;
  unsigned short* arow = Act + ((size_t)(b * T_LEN + t) * E_DIM + hd * VD);
  arow[lane]      = f2bf(x0 * s * g[lane]);
  arow[lane + 64] = f2bf(x1 * s * g[lane + 64]);
}

extern "C" void kernel_launch(void* const* d_in, const int* in_sizes, int n_in,
                              void* d_out, int out_size, void* d_ws, size_t ws_size,
                              hipStream_t stream) {
  (void)in_sizes; (void)n_in; (void)out_size; (void)ws_size;
  const float* x   = (const float*)d_in[0];
  const float* Wq  = (const float*)d_in[1];
  const float* Wk  = (const float*)d_in[2];
  const float* Wv  = (const float*)d_in[3];
  const float* Wo  = (const float*)d_in[4];
  const float* lq1 = (const float*)d_in[5];
  const float* lk1 = (const float*)d_in[6];
  const float* lq2 = (const float*)d_in[7];
  const float* lk2 = (const float*)d_in[8];
  const float* g   = (const float*)d_in[9];

  char* p = (char*)d_ws;
  unsigned short* XBF = (unsigned short*)p; p += (size_t)M_ROWS * E_DIM * 2;
  unsigned short* WQB = (unsigned short*)p; p += (size_t)E_DIM * E_DIM * 2;  // Wq (scaled)
  unsigned short* WKB = (unsigned short*)p; p += (size_t)E_DIM * E_DIM * 2;  // Wk (adjacent!)
  unsigned short* WVB = (unsigned short*)p; p += (size_t)E_DIM * E_DIM * 2;
  unsigned short* WOB = (unsigned short*)p; p += (size_t)E_DIM * E_DIM * 2;
  unsigned short* QKB = (unsigned short*)p; p += (size_t)M_ROWS * QKLD * 2;  // merged Q|K
  unsigned short* VTB = (unsigned short*)p; p += (size_t)M_ROWS * E_DIM * 2;
  float*          OH  = (float*)p;          p += (size_t)B_SZ * HH * T_LEN * VD * 4;
  unsigned short* ACT = (unsigned short*)p; p += (size_t)M_ROWS * E_DIM * 2;

  cast_bf16<<<2048, 256, 0, stream>>>(x,  XBF, M_ROWS * E_DIM / 4, 1.0f);
  cast_bf16<<<1024, 256, 0, stream>>>(Wq, WQB, E_DIM * E_DIM / 4, 0.125f);  // fold D^-0.5
  cast_bf16<<<1024, 256, 0, stream>>>(Wk, WKB, E_DIM * E_DIM / 4, 1.0f);
  cast_bf16<<<1024, 256, 0, stream>>>(Wv, WVB, E_DIM * E_DIM / 4, 1.0f);
  cast_bf16<<<1024, 256, 0, stream>>>(Wo, WOB, E_DIM * E_DIM / 4, 1.0f);

  // merged Q|K projection: B = stacked [WQB; WKB] (contiguous), N = 4096
  dim3 gqk(M_ROWS / 128, (2 * E_DIM) / 128);
  gemm_bt<0><<<gqk, 256, 0, stream>>>(XBF, WQB, QKB, M_ROWS, 2 * E_DIM, E_DIM, 1.0f);
  // V^T = Wv * X^T  (operand swap -> coalesced transposed output [E, M_ROWS])
  dim3 gt(E_DIM / 128, M_ROWS / 128);
  gemm_bt<0><<<gt, 256, 0, stream>>>(WVB, XBF, VTB, E_DIM, M_ROWS, E_DIM, 1.0f);

  flash_attn_mfma<<<dim3(NQT / 2, HH, B_SZ), 256, 0, stream>>>(QKB, VTB, OH);

  combine_norm<<<B_SZ * T_LEN * NH / 4, 256, 0, stream>>>(OH, lq1, lk1, lq2, lk2, g, ACT);

  dim3 gg(M_ROWS / 128, E_DIM / 128);
  gemm_bt<1><<<gg, 256, 0, stream>>>(ACT, WOB, d_out, M_ROWS, E_DIM, E_DIM, 1.0f);
}